// Round 9
// baseline (3083.492 us; speedup 1.0000x reference)
//
#include <hip/hip_runtime.h>

typedef __attribute__((ext_vector_type(8))) short short8;
typedef __attribute__((ext_vector_type(4))) float floatx4;
typedef unsigned int uint;
typedef unsigned short ushort;
typedef unsigned long long ull;

#define B_ 512
#define S_ 200
#define H_ 512
#define VOCAB_ 2002

__device__ __forceinline__ ushort f2bfbits(float f) {
  union { float f; uint u; } c; c.f = f;
  uint u = c.u;
  u += 0x7fffu + ((u >> 16) & 1u);   // RNE
  return (ushort)(u >> 16);
}
__device__ __forceinline__ float bf2f_(ushort u) {
  union { uint i; float f; } c; c.i = ((uint)u) << 16; return c.f;
}
__device__ __forceinline__ float sigmoidf_(float x) { return 1.f / (1.f + __expf(-x)); }
__device__ __forceinline__ float tanhf_(float x) { return 2.f / (1.f + __expf(-2.f * x)) - 1.f; }
__device__ __forceinline__ float clamp30(float x) { return fminf(fmaxf(x, -30.f), 30.f); }

// split f32[8] -> (hi, lo) bf16 short8 pair; hi+lo carries ~16 mantissa bits
__device__ __forceinline__ void split8(const float* p, short8& hi, short8& lo) {
#pragma unroll
  for (int j = 0; j < 8; ++j) {
    const float f = p[j];
    const ushort h = f2bfbits(f);
    hi[j] = (short)h;
    lo[j] = (short)f2bfbits(f - bf2f_(h));
  }
}

// ---------------------------------------------------------------------------
// K1: EncGates[v][n] = emb[v]·W_ih[n]  (f32-accurate via 3-product split MFMA)
// ---------------------------------------------------------------------------
template <typename ET>
__global__ void encg_kernel(const float* __restrict__ emb, const float* __restrict__ Wih,
                            ET* __restrict__ encg) {
  const int w = threadIdx.x >> 6, l = threadIdx.x & 63;
  const int ln = l & 15, lk = l >> 4;
  const int n = (blockIdx.x * 4 + w) * 16 + ln;
  const int m = blockIdx.y * 16 + ln;
  const int mA = (m < VOCAB_) ? m : 0;
  const float* ap = emb + (size_t)mA * 512 + lk * 8;
  const float* bp = Wih + (size_t)n * 512 + lk * 8;
  floatx4 acc = {0.f, 0.f, 0.f, 0.f};
#pragma unroll 4
  for (int kk = 0; kk < 16; ++kk) {
    short8 ah, al, bh, bl;
    split8(ap + kk * 32, ah, al);
    split8(bp + kk * 32, bh, bl);
    acc = __builtin_amdgcn_mfma_f32_16x16x32_bf16(ah, bh, acc, 0, 0, 0);
    acc = __builtin_amdgcn_mfma_f32_16x16x32_bf16(ah, bl, acc, 0, 0, 0);
    acc = __builtin_amdgcn_mfma_f32_16x16x32_bf16(al, bh, acc, 0, 0, 0);
  }
#pragma unroll
  for (int r = 0; r < 4; ++r) {
    const int mo = blockIdx.y * 16 + lk * 4 + r;   // C/D: row=(lane>>4)*4+reg
    if (mo < VOCAB_) {
      if constexpr (sizeof(ET) == 2)
        encg[(size_t)mo * 2048 + n] = (ET)f2bfbits(acc[r]);
      else
        encg[(size_t)mo * 2048 + n] = acc[r];       // col = lane&15
    }
  }
}

// ---------------------------------------------------------------------------
// K2: et[s][b] = sigmoid(P[u].Q[k] + Pb[u] + Qb[k]); f32. grid (200,128)x256.
// ---------------------------------------------------------------------------
__global__ void mf_kernel(const int* __restrict__ us, const int* __restrict__ ss,
                          const float* __restrict__ P, const float* __restrict__ Q,
                          const float* __restrict__ Pb, const float* __restrict__ Qb,
                          float* __restrict__ etb) {
  const int s = blockIdx.x;
  const int w = threadIdx.x >> 6, l = threadIdx.x & 63;
  const int b = blockIdx.y * 4 + w;
  const int u = us[b * S_ + s];
  const int k = ss[b * S_ + s];
  const float4 p0 = *(const float4*)(P + (size_t)u * 512 + l * 8);
  const float4 p1 = *(const float4*)(P + (size_t)u * 512 + l * 8 + 4);
  const float4 q0 = *(const float4*)(Q + (size_t)k * 512 + l * 8);
  const float4 q1 = *(const float4*)(Q + (size_t)k * 512 + l * 8 + 4);
  float dot = p0.x*q0.x + p0.y*q0.y + p0.z*q0.z + p0.w*q0.w
            + p1.x*q1.x + p1.y*q1.y + p1.z*q1.z + p1.w*q1.w;
#pragma unroll
  for (int off = 32; off > 0; off >>= 1) dot += __shfl_xor(dot, off);
  if (l == 0)
    etb[s * B_ + b] = sigmoidf_(dot + Pb[u] + Qb[k]);
}

// ---------------------------------------------------------------------------
// K3: recurrent LSTM. 256 blocks x 512 thr, 1 block/CU.
// Mapping (tuned for bid%8 XCD round-robin): g=(bid&7)*2+((bid>>3)&1),
// ns=bid>>4 -> a group's 16 blocks co-locate on one XCD if round-robin holds.
// Runtime CENSUS verifies per group via s_getreg(HW_REG_XCC_ID) [m09]
// published through the agent-scope slot fabric.
//   fast path (co-located): plain write-through stores (dirty in XCD L2) +
//     volatile (sc0) loads/polls -> all exchange served by the shared TCC
//     (~200cy, 34TB/s) instead of the MALL (~900cy) — same-XCD requests
//     cannot see stale data (all traffic routes through the one TCC).
//   fallback (split group): r8's agent-scope path, verbatim.
// ---------------------------------------------------------------------------
template <typename ET>
__global__ __launch_bounds__(512, 2) void lstm_kernel(
    const int* __restrict__ tok, const ET* __restrict__ encg,
    const float* __restrict__ etb, const float* __restrict__ Whh,
    const float* __restrict__ bih, const float* __restrict__ bhh,
    ushort* ht_hi, ushort* ht_lo, int* ctr) {
  __shared__ __align__(16) ushort Ah_lds[32 * 528];   // 33,792 B
  __shared__ __align__(16) ushort Al_lds[32 * 528];   // 33,792 B
  __shared__ __align__(16) float gp_lds[128 * 36];    // 18,432 B
  __shared__ int cen_lds[16];
  __shared__ int fast_flag;

  const int bid = blockIdx.x;
  const int g = (bid & 7) * 2 + ((bid >> 3) & 1);
  const int ns = bid >> 4;
  const int b0 = g * 32, h0 = ns * 32;
  const int tid = threadIdx.x;
  const int w = tid >> 6, l = tid & 63;
  const int ln = l & 15, lk = l >> 4;
  const int q = w >> 1;                 // gate (i,f,g,o)
  const int c0 = (w & 1) * 16;          // col sub-tile within 32 h-units

  // step slots (64-B stride): group g's producer ns at ctr[g*256 + ns*16]
  int* const myslot = ctr + g * 256 + ns * 16;
  int* const gslots = ctr + g * 256;
  // census slots: +4096 ints
  int* const census = ctr + 4096;

  // --- publish XCD id (hwreg 20, bits[3:0]) immediately ---
  if (tid == 0) {
    const int xcd = (int)__builtin_amdgcn_s_getreg(6164);  // (4-1)<<11 | 20
    __hip_atomic_store(census + (g * 16 + ns) * 16, xcd + 1,
                       __ATOMIC_RELAXED, __HIP_MEMORY_SCOPE_AGENT);
  }

  // --- preload + split this wave's W_hh rows (16 gate cols), once ---
  short8 Bh[16], Bl[16];
  {
    const float* wr = Whh + (size_t)(q * 512 + h0 + c0 + ln) * 512 + lk * 8;
#pragma unroll 4
    for (int kk = 0; kk < 16; ++kk)
      split8(wr + kk * 32, Bh[kk], Bl[kk]);
  }

  // --- census poll (overlapped after W preload) ---
  if (tid < 16) {
    int v;
    do {
      v = __hip_atomic_load(census + (g * 16 + tid) * 16,
                            __ATOMIC_RELAXED, __HIP_MEMORY_SCOPE_AGENT);
    } while (v == 0);
    cen_lds[tid] = v;
  }
  __syncthreads();
  if (tid == 0) {
    int f = 1;
#pragma unroll
    for (int i = 1; i < 16; ++i) f &= (cen_lds[i] == cen_lds[0]);
    fast_flag = f;
  }
  __syncthreads();
  const bool fastp = (fast_flag != 0);

  const int sr = tid >> 4;              // batch row within group (0..31)
  const int sc = tid & 15;              // 32-elem chunk / h-pair index
  const int hh = sc * 2;
  const int bg = b0 + sr;
  float ct0 = 0.f, ct1 = 0.f;

  float bs[4][2];
#pragma unroll
  for (int qq = 0; qq < 4; ++qq) {
    const int col = qq * 512 + h0 + hh;
    bs[qq][0] = bih[col] + bhh[col];
    bs[qq][1] = bih[col + 1] + bhh[col + 1];
  }

  for (int s = 0; s < S_; ++s) {
    // ---- prefetch nonlinearity inputs (ht-independent) ----
    const int tv = tok[bg * S_ + s];
    float ev = etb[s * B_ + bg];
    float ex[4], ey[4];
#pragma unroll
    for (int qq = 0; qq < 4; ++qq) {
      if constexpr (sizeof(ET) == 2) {
        const uint e2 = *(const uint*)((const ushort*)encg + (size_t)tv * 2048 + qq * 512 + h0 + hh);
        ex[qq] = bf2f_((ushort)(e2 & 0xffffu)); ey[qq] = bf2f_((ushort)(e2 >> 16));
      } else {
        const float2 e = *(const float2*)((const float*)encg + (size_t)tv * 2048 + qq * 512 + h0 + hh);
        ex[qq] = e.x; ey[qq] = e.y;
      }
    }

    if (s > 0) {
      if (tid < 16) {   // lane tid spins on producer tid's slot
        if (fastp) {
          while (((volatile const int*)gslots)[tid * 16] < s) {}
        } else {
          while (__hip_atomic_load(gslots + tid * 16, __ATOMIC_RELAXED,
                                   __HIP_MEMORY_SCOPE_AGENT) < s) {}
        }
      }
      __syncthreads();
    }
    const size_t rdo = (size_t)(s & 1) * (B_ * H_);
    const size_t wro = (size_t)((s & 1) ^ 1) * (B_ * H_);

    // ---- stage ht(s) hi+lo rows [b0..b0+32) -> LDS ----
    {
      const size_t go = rdo + (size_t)(b0 + sr) * 512 + sc * 32;
      const int lo_ = sr * 528 + sc * 32;
      if (fastp) {
        volatile const ull* sh = (volatile const ull*)(ht_hi + go);
        volatile const ull* sl = (volatile const ull*)(ht_lo + go);
#pragma unroll
        for (int i = 0; i < 8; ++i) *(ull*)(Ah_lds + lo_ + i * 4) = sh[i];
#pragma unroll
        for (int i = 0; i < 8; ++i) *(ull*)(Al_lds + lo_ + i * 4) = sl[i];
      } else {
#pragma unroll
        for (int i = 0; i < 8; ++i)
          *(ull*)(Ah_lds + lo_ + i * 4) =
              __hip_atomic_load((const ull*)(ht_hi + go + i * 4), __ATOMIC_RELAXED, __HIP_MEMORY_SCOPE_AGENT);
#pragma unroll
        for (int i = 0; i < 8; ++i)
          *(ull*)(Al_lds + lo_ + i * 4) =
              __hip_atomic_load((const ull*)(ht_lo + go + i * 4), __ATOMIC_RELAXED, __HIP_MEMORY_SCOPE_AGENT);
      }
    }
    __syncthreads();

    // ---- 3-product split MFMA: gates[32 x 16cols] per wave ----
    floatx4 acc[2];
    acc[0] = (floatx4){0.f, 0.f, 0.f, 0.f};
    acc[1] = (floatx4){0.f, 0.f, 0.f, 0.f};
#pragma unroll
    for (int mt = 0; mt < 2; ++mt)
#pragma unroll
      for (int kk = 0; kk < 16; ++kk) {
        const int ao = (mt * 16 + ln) * 528 + kk * 32 + lk * 8;
        const short8 ah = *(const short8*)(Ah_lds + ao);
        const short8 al = *(const short8*)(Al_lds + ao);
        acc[mt] = __builtin_amdgcn_mfma_f32_16x16x32_bf16(ah, Bh[kk], acc[mt], 0, 0, 0);
        acc[mt] = __builtin_amdgcn_mfma_f32_16x16x32_bf16(ah, Bl[kk], acc[mt], 0, 0, 0);
        acc[mt] = __builtin_amdgcn_mfma_f32_16x16x32_bf16(al, Bh[kk], acc[mt], 0, 0, 0);
      }
#pragma unroll
    for (int mt = 0; mt < 2; ++mt)
      *(floatx4*)(gp_lds + (w * 16 + ln) * 36 + mt * 16 + lk * 4) = acc[mt];
    __syncthreads();

    // ---- nonlinearity: thread owns (row sr, h-units hh, hh+1) ----
    {
      ev = fminf(fmaxf(ev, 0.f), 1.f);
      float Gv[4][2];
#pragma unroll
      for (int qq = 0; qq < 4; ++qq) {
        Gv[qq][0] = clamp30(gp_lds[(qq * 32 + hh) * 36 + sr] + ex[qq] + bs[qq][0]);
        Gv[qq][1] = clamp30(gp_lds[(qq * 32 + hh + 1) * 36 + sr] + ey[qq] + bs[qq][1]);
      }
      const float scale = 1.f + ev;
      float c0v = ct0 * scale;
      c0v = sigmoidf_(Gv[1][0]) * c0v + sigmoidf_(Gv[0][0]) * tanhf_(Gv[2][0]);
      const float h0v = sigmoidf_(Gv[3][0]) * tanhf_(c0v);
      ct0 = c0v;                                   // UNCLAMPED (ref semantics)
      float c1v = ct1 * scale;
      c1v = sigmoidf_(Gv[1][1]) * c1v + sigmoidf_(Gv[0][1]) * tanhf_(Gv[2][1]);
      const float h1v = sigmoidf_(Gv[3][1]) * tanhf_(c1v);
      ct1 = c1v;
      const ushort h0h = f2bfbits(h0v), h1h = f2bfbits(h1v);
      const ushort h0l = f2bfbits(h0v - bf2f_(h0h)), h1l = f2bfbits(h1v - bf2f_(h1h));
      const size_t wo = wro + (size_t)bg * 512 + h0 + hh;
      const uint ph = (uint)h0h | ((uint)h1h << 16);
      const uint pl = (uint)h0l | ((uint)h1l << 16);
      if (fastp) {
        *(uint*)(ht_hi + wo) = ph;    // write-through -> dirty in XCD L2
        *(uint*)(ht_lo + wo) = pl;
      } else {
        __hip_atomic_store((uint*)(ht_hi + wo), ph, __ATOMIC_RELAXED, __HIP_MEMORY_SCOPE_AGENT);
        __hip_atomic_store((uint*)(ht_lo + wo), pl, __ATOMIC_RELAXED, __HIP_MEMORY_SCOPE_AGENT);
      }
    }
    __syncthreads();   // per-wave s_waitcnt vmcnt(0) before s_barrier drains
                       // ALL waves' stores to the coherence point (L2 / MALL)
    if (tid == 0) {
      if (fastp) ((volatile int*)myslot)[0] = s + 1;
      else __hip_atomic_store(myslot, s + 1, __ATOMIC_RELAXED, __HIP_MEMORY_SCOPE_AGENT);
    }
  }
}

// ---------------------------------------------------------------------------
// K4: out[b] = sigmoid( (ht_hi+ht_lo)[b] . dec_W[tgt[b]] + dec_b[tgt[b]] )
// grid 128 x 256 (one wave per batch row). Final ht is in buffer parity 0.
// (Separate dispatch: all L2s drained/visible at kernel boundary.)
// ---------------------------------------------------------------------------
__global__ void dec_kernel(const ushort* __restrict__ hthi, const ushort* __restrict__ htlo,
                           const float* __restrict__ decW, const float* __restrict__ decb,
                           const int* __restrict__ tgt, float* __restrict__ out) {
  const int w = threadIdx.x >> 6, l = threadIdx.x & 63;
  const int b = blockIdx.x * 4 + w;
  const int t = tgt[b];
  const uint4 hv = *(const uint4*)(hthi + (size_t)b * 512 + l * 8);
  const uint4 lv = *(const uint4*)(htlo + (size_t)b * 512 + l * 8);
  const float4 w0 = *(const float4*)(decW + (size_t)t * 512 + l * 8);
  const float4 w1 = *(const float4*)(decW + (size_t)t * 512 + l * 8 + 4);
  const uint ha[4] = {hv.x, hv.y, hv.z, hv.w};
  const uint la[4] = {lv.x, lv.y, lv.z, lv.w};
  float hf[8];
#pragma unroll
  for (int i = 0; i < 4; ++i) {
    hf[2*i]   = bf2f_((ushort)(ha[i] & 0xffffu)) + bf2f_((ushort)(la[i] & 0xffffu));
    hf[2*i+1] = bf2f_((ushort)(ha[i] >> 16))     + bf2f_((ushort)(la[i] >> 16));
  }
  float dot = hf[0]*w0.x + hf[1]*w0.y + hf[2]*w0.z + hf[3]*w0.w
            + hf[4]*w1.x + hf[5]*w1.y + hf[6]*w1.z + hf[7]*w1.w;
#pragma unroll
  for (int off = 32; off > 0; off >>= 1) dot += __shfl_xor(dot, off);
  if (l == 0) out[b] = sigmoidf_(dot + decb[t]);
}

extern "C" void kernel_launch(void* const* d_in, const int* in_sizes, int n_in,
                              void* d_out, int out_size, void* d_ws, size_t ws_size,
                              hipStream_t stream) {
  (void)in_sizes; (void)n_in; (void)out_size;
  const int* main_input = (const int*)d_in[0];
  const int* target_id  = (const int*)d_in[1];
  const int* user_seq   = (const int*)d_in[2];
  const int* skill_seq  = (const int*)d_in[3];
  const float* enc_emb  = (const float*)d_in[4];
  const float* P        = (const float*)d_in[5];
  const float* Q        = (const float*)d_in[6];
  const float* Pb       = (const float*)d_in[7];
  const float* Qb       = (const float*)d_in[8];
  const float* W_ih     = (const float*)d_in[9];
  const float* W_hh     = (const float*)d_in[10];
  const float* b_ih     = (const float*)d_in[11];
  const float* b_hh     = (const float*)d_in[12];
  const float* dec_W    = (const float*)d_in[13];
  const float* dec_b    = (const float*)d_in[14];
  float* out = (float*)d_out;

  // workspace layout:
  //   [0)          ht_hi  2*512*512 bf16 = 1,048,576
  //   [1,048,576)  ht_lo  1,048,576                   -> 2,097,152
  //   [2,097,152)  ctr    256 step slots + 256 census slots x 64 B = 32,768
  //   [2,129,920)  etb    200*512 f32 = 409,600       -> 2,539,520
  //   [2,539,520)  encg   f32 16,400,384 (else bf16 8,200,192)
  char* wsb = (char*)d_ws;
  ushort* ht_hi = (ushort*)wsb;
  ushort* ht_lo = (ushort*)(wsb + 1048576);
  int* ctr = (int*)(wsb + 2097152);
  float* etb = (float*)(wsb + 2129920);
  char* encb = wsb + 2539520;
  const bool enc32 = ws_size >= (size_t)2539520 + 16400384;

  hipMemsetAsync(wsb, 0, 2129920, stream);   // ht(0)=0, step+census slots=0

  if (enc32)
    encg_kernel<float><<<dim3(32, 126), dim3(256), 0, stream>>>(enc_emb, W_ih, (float*)encb);
  else
    encg_kernel<ushort><<<dim3(32, 126), dim3(256), 0, stream>>>(enc_emb, W_ih, (ushort*)encb);
  mf_kernel<<<dim3(200, 128), dim3(256), 0, stream>>>(user_seq, skill_seq, P, Q, Pb, Qb, etb);
  if (enc32)
    lstm_kernel<float><<<dim3(256), dim3(512), 0, stream>>>(
        main_input, (const float*)encb, etb, W_hh, b_ih, b_hh, ht_hi, ht_lo, ctr);
  else
    lstm_kernel<ushort><<<dim3(256), dim3(512), 0, stream>>>(
        main_input, (const ushort*)encb, etb, W_hh, b_ih, b_hh, ht_hi, ht_lo, ctr);
  dec_kernel<<<dim3(128), dim3(256), 0, stream>>>(ht_hi, ht_lo, dec_W, dec_b, target_id, out);
}